// Round 3
// baseline (682.594 us; speedup 1.0000x reference)
//
#include <hip/hip_runtime.h>
#include <hip/hip_bf16.h>

#define B_N 16
#define U_N 2048
#define S_N 512
#define D_N 128
#define NEGV (-1000000000.0f)
#define INV_SQRT_D 0.08838834764831845f

typedef unsigned long long ull;
typedef __attribute__((ext_vector_type(8))) short bf16x8;
typedef __attribute__((ext_vector_type(4))) float f32x4;
typedef __attribute__((ext_vector_type(2))) _Float16 f16x2;

// ---------- helpers ----------
__device__ __forceinline__ unsigned monof(float v) {
    unsigned b = __float_as_uint(v);
    return (b & 0x80000000u) ? ~b : (b | 0x80000000u);
}
__device__ __forceinline__ float unmonof(unsigned m) {
    unsigned b = (m & 0x80000000u) ? (m & 0x7fffffffu) : ~m;
    return __uint_as_float(b);
}
__device__ __forceinline__ unsigned short f2bf(float x) {  // RNE fp32->bf16
    unsigned u = __float_as_uint(x);
    return (unsigned short)((u + 0x7fffu + ((u >> 16) & 1u)) >> 16);
}

// ---------- init: zero state, pack needs/caps/fd masks ----------
__global__ void init_state(const float* __restrict__ servers, const float* __restrict__ users,
                           const int* __restrict__ fd_onehot,
                           unsigned* allocU, uint4* alloc3, unsigned* rcArr, unsigned* seenArr,
                           float* logp, float* capA, float* invA, unsigned* fdm, float* nds) {
    int i = blockIdx.x * 256 + threadIdx.x;  // 2048 blocks -> 524288 threads
    if (i < B_N * U_N * 16) allocU[i] = 0u;
    if (i < B_N * U_N) {
        rcArr[i] = 0u; seenArr[i] = 0u; logp[i] = 0.f;
        alloc3[i] = make_uint4(0xFFFFFFFFu, 0xFFFFFFFFu, 0xFFFFFFFFu, 0xFFFFFFFFu);
        const float* up = users + (size_t)i * 6;
        nds[i * 4 + 0] = up[2]; nds[i * 4 + 1] = up[3];
        nds[i * 4 + 2] = up[4]; nds[i * 4 + 3] = up[5];
    }
    if (i < B_N * S_N) {
        const float* sp = servers + (size_t)i * 7;
        float4 c = make_float4(sp[3], sp[4], sp[5], sp[6]);
        ((float4*)capA)[i] = c;
        ((float4*)invA)[i] = make_float4(1.f / fmaxf(c.x, 1e-6f), 1.f / fmaxf(c.y, 1e-6f),
                                         1.f / fmaxf(c.z, 1e-6f), 1.f / fmaxf(c.w, 1e-6f));
        unsigned w = 0u;
        const int* fp = fd_onehot + (size_t)i * 32;
        #pragma unroll
        for (int f = 0; f < 32; ++f) w |= (fp[f] != 0 ? 1u : 0u) << f;
        fdm[i] = w;
    }
}

// ---------- pack connect (B,U,S) int32 -> (B,U,S-bits): ballot per wave ----------
__global__ void pack_connect(const int* __restrict__ connect, ull* __restrict__ connU) {
    int i = blockIdx.x * 4 + (threadIdx.x >> 6);  // row index in [0, B*U)
    int lane = threadIdx.x & 63;
    const int* row = connect + (size_t)i * S_N;
    #pragma unroll
    for (int c = 0; c < 8; ++c) {
        ull m = __ballot(row[c * 64 + lane] != 0);
        if (lane == 0) connU[(size_t)i * 8 + c] = m;
    }
}

// ---------- generic fp32 GEMM: C[z][m][n] = scale * sum_k (A[z][m][k](+abias[k])) * B[n][k]
// OUTMODE: 0 = fp32 only, 1 = bf16 only, 2 = both
template <bool ABIAS, int OUTMODE>
__global__ __launch_bounds__(256) void gemm_nt(const float* __restrict__ A, const float* __restrict__ Bm,
                                               const float* __restrict__ abias, float* __restrict__ C,
                                               unsigned short* __restrict__ C16,
                                               int M, int N, int K, float scale) {
    __shared__ float As[16][68];
    __shared__ float Bs[16][68];
    int z = blockIdx.z;
    const float* Ab = A + (size_t)z * M * K;
    const float* Bb = Bm;
    int m0 = blockIdx.x * 64, n0 = blockIdx.y * 64;
    int tid = threadIdx.x;
    int tx = tid & 15, ty = tid >> 4;
    int lrow = tid >> 2, lk = (tid & 3) * 4;
    float acc[4][4] = {};
    for (int k0 = 0; k0 < K; k0 += 16) {
        float4 av = *(const float4*)(Ab + (size_t)(m0 + lrow) * K + k0 + lk);
        float4 bv = *(const float4*)(Bb + (size_t)(n0 + lrow) * K + k0 + lk);
        if (ABIAS) {
            av.x += abias[k0 + lk]; av.y += abias[k0 + lk + 1];
            av.z += abias[k0 + lk + 2]; av.w += abias[k0 + lk + 3];
        }
        __syncthreads();
        As[lk + 0][lrow] = av.x; As[lk + 1][lrow] = av.y; As[lk + 2][lrow] = av.z; As[lk + 3][lrow] = av.w;
        Bs[lk + 0][lrow] = bv.x; Bs[lk + 1][lrow] = bv.y; Bs[lk + 2][lrow] = bv.z; Bs[lk + 3][lrow] = bv.w;
        __syncthreads();
        #pragma unroll
        for (int kk = 0; kk < 16; ++kk) {
            float4 a = *(const float4*)&As[kk][ty * 4];
            float4 bq = *(const float4*)&Bs[kk][tx * 4];
            float ar[4] = {a.x, a.y, a.z, a.w}, br[4] = {bq.x, bq.y, bq.z, bq.w};
            #pragma unroll
            for (int ii = 0; ii < 4; ++ii)
                #pragma unroll
                for (int jj = 0; jj < 4; ++jj) acc[ii][jj] += ar[ii] * br[jj];
        }
    }
    #pragma unroll
    for (int ii = 0; ii < 4; ++ii) {
        float4 o = make_float4(acc[ii][0] * scale, acc[ii][1] * scale,
                               acc[ii][2] * scale, acc[ii][3] * scale);
        size_t idx = (size_t)z * M * N + (size_t)(m0 + ty * 4 + ii) * N + n0 + tx * 4;
        if (OUTMODE != 1) *(float4*)(C + idx) = o;
        if (OUTMODE != 0) {
            ushort4 ob;
            ob.x = f2bf(o.x); ob.y = f2bf(o.y); ob.z = f2bf(o.z); ob.w = f2bf(o.w);
            *(ushort4*)(C16 + idx) = ob;
        }
    }
}

// ---------- M2[d][c] = inv_sqrt_d * sum_e ptr_k_w[d,e]*state_proj_w[e,c] ----------
__global__ void m2_kernel(const float* __restrict__ kw, const float* __restrict__ spw, float* __restrict__ M2) {
    int t = threadIdx.x;
    if (t < 512) {
        int d = t >> 2, c = t & 3;
        float acc = 0.f;
        for (int e = 0; e < 128; ++e) acc += kw[d * 128 + e] * spw[e * 4 + c];
        M2[t] = acc * INV_SQRT_D;
    }
}

// ---------- qm[b,u,c] = sum_d q[b,u,d]*M2[d,c] ----------
__global__ void qm_kernel(const float* __restrict__ q, const float* __restrict__ M2, float* __restrict__ qm) {
    __shared__ float qs[64][129];
    __shared__ float m2s[512];
    int b = blockIdx.y, u0 = blockIdx.x * 64;
    int t = threadIdx.x;
    for (int i = t; i < 512; i += 256) m2s[i] = M2[i];
    #pragma unroll
    for (int it = 0; it < 8; ++it) {
        int f4 = t + 256 * it;
        int row = f4 >> 5;
        int col = (f4 & 31) * 4;
        float4 v = *(const float4*)(q + ((size_t)(b * U_N + u0 + row)) * D_N + col);
        qs[row][col] = v.x; qs[row][col + 1] = v.y; qs[row][col + 2] = v.z; qs[row][col + 3] = v.w;
    }
    __syncthreads();
    int ul = t >> 2, c = t & 3;
    float acc = 0.f;
    for (int d = 0; d < 128; ++d) acc += qs[ul][d] * m2s[d * 4 + c];
    qm[((size_t)(b * U_N + u0 + ul)) * 4 + c] = acc;
}

// ---------- qk MFMA: qkh[b][u][s] = fp16( sum_k qb[b][u][k]*kb[b][s][k] ), bf16 inputs.
// Block tile 128u x 64s, K=128 in one pass. No A/B LDS staging (frag loads are
// naturally 16x64B-coalesced; B tile is L1-resident). LDS only for C transpose.
__global__ __launch_bounds__(256) void qk_mfma(const unsigned short* __restrict__ qb,
                                               const unsigned short* __restrict__ kb,
                                               _Float16* __restrict__ qkh) {
    const int b = blockIdx.z, u0 = blockIdx.x * 128, s0 = blockIdx.y * 64;
    const int t = threadIdx.x, w = t >> 6, l = t & 63;
    const int lr = l & 15, lq = l >> 4;
    const unsigned short* Ab = qb + ((size_t)(b * U_N + u0 + w * 32 + lr)) * D_N + lq * 8;
    const unsigned short* Bb = kb + ((size_t)(b * S_N + s0 + lr)) * D_N + lq * 8;
    f32x4 acc[2][4] = {};
    #pragma unroll
    for (int kt = 0; kt < 4; ++kt) {
        bf16x8 a0 = *(const bf16x8*)(Ab + kt * 32);
        bf16x8 a1 = *(const bf16x8*)(Ab + 16 * D_N + kt * 32);
        #pragma unroll
        for (int c = 0; c < 4; ++c) {
            bf16x8 bf = *(const bf16x8*)(Bb + c * 16 * D_N + kt * 32);
            acc[0][c] = __builtin_amdgcn_mfma_f32_16x16x32_bf16(a0, bf, acc[0][c], 0, 0, 0);
            acc[1][c] = __builtin_amdgcn_mfma_f32_16x16x32_bf16(a1, bf, acc[1][c], 0, 0, 0);
        }
    }
    __shared__ _Float16 Cs[128][72];
    #pragma unroll
    for (int mt = 0; mt < 2; ++mt)
        #pragma unroll
        for (int c = 0; c < 4; ++c)
            #pragma unroll
            for (int r = 0; r < 4; ++r)
                Cs[w * 32 + mt * 16 + lq * 4 + r][c * 16 + lr] = (_Float16)acc[mt][c][r];
    __syncthreads();
    #pragma unroll
    for (int k = 0; k < 4; ++k) {
        int row = (t >> 3) + k * 32;
        int sg = (t & 7) * 8;
        uint4 v = *(const uint4*)&Cs[row][sg];
        *(uint4*)(qkh + ((size_t)(b * U_N + u0 + row)) * S_N + s0 + sg) = v;
    }
}

// ---------- K1: servers-in-lanes scoring. block = (b, 32-user chunk); lane owns 2 servers.
__global__ __launch_bounds__(256) void iter_score(
    const _Float16* __restrict__ qkh, const float* __restrict__ qm4,
    const float* __restrict__ nds, const unsigned* __restrict__ connU,
    const uint4* __restrict__ alloc3, const unsigned* __restrict__ rcArr,
    const unsigned* __restrict__ seenArr, const unsigned* __restrict__ fdm_,
    const float* __restrict__ capA, const float* __restrict__ invA,
    const float* __restrict__ usw, const float* __restrict__ sbp, const float* __restrict__ fdbp,
    ull* __restrict__ keypart, float* __restrict__ sumpart) {
    const int tid = threadIdx.x;
    const int b = blockIdx.x & 15;
    const int ublk = blockIdx.x >> 4;     // 0..63, 32 users each
    const int u0 = ublk << 5;
    const int wid = tid >> 6, lane = tid & 63;
    const int s0 = wid * 128 + lane * 2;  // this thread's two servers
    const float w0 = usw[0], w1 = usw[1], w2 = usw[2], sb = sbp[0], fdb = fdbp[0];
    float ub[4];
    #pragma unroll
    for (int r = 0; r < 4; ++r)
        ub[r] = sb + w0 * (r * (1.0f / 3.0f)) + w1 * ((3 - r) * (1.0f / 3.0f)) + (r == 2 ? w2 : 0.0f);
    const int bs = b * S_N + s0;
    const float4 cap0 = ((const float4*)capA)[bs], cap1 = ((const float4*)capA)[bs + 1];
    const float4 iv0 = ((const float4*)invA)[bs], iv1 = ((const float4*)invA)[bs + 1];
    const float4 cr0 = make_float4(cap0.x * iv0.x, cap0.y * iv0.y, cap0.z * iv0.z, cap0.w * iv0.w);
    const float4 cr1 = make_float4(cap1.x * iv1.x, cap1.y * iv1.y, cap1.z * iv1.z, cap1.w * iv1.w);
    const unsigned f0 = fdm_[bs], f1 = fdm_[bs + 1];
    const unsigned us0 = (unsigned)s0, us1 = (unsigned)(s0 + 1);
    const int shift = s0 & 31;
    ull k0 = 0ULL, k1 = 0ULL;
    float e0 = 0.f, e1 = 0.f;
    const _Float16* qkrow = qkh + ((size_t)(b * U_N + u0)) * S_N + s0;
    const int gub = b * U_N + u0;
    #pragma unroll 4
    for (int uu = 0; uu < 32; ++uu) {
        const int gu = gub + uu;
        const f16x2 hv = *(const f16x2*)(qkrow + (size_t)uu * S_N);
        const float bl0 = (float)hv.x, bl1 = (float)hv.y;
        const float4 qmv = ((const float4*)qm4)[gu];   // wave-uniform -> scalar loads
        const float4 ndv = ((const float4*)nds)[gu];
        const unsigned rcu = rcArr[gu], snu = seenArr[gu];
        const uint4 al = alloc3[gu];
        const unsigned cw = connU[gu * 16 + (s0 >> 5)];
        const bool needm = rcu < 3u;
        const float add = ub[rcu & 3u];
        const bool aok0 = (al.x != us0) & (al.y != us0) & (al.z != us0);
        const bool aok1 = (al.x != us1) & (al.y != us1) & (al.z != us1);
        const bool ful0 = (cap0.x >= ndv.x) & (cap0.y >= ndv.y) & (cap0.z >= ndv.z) & (cap0.w >= ndv.w);
        const bool ful1 = (cap1.x >= ndv.x) & (cap1.y >= ndv.y) & (cap1.z >= ndv.z) & (cap1.w >= ndv.w);
        const bool el0 = (((cw >> shift) & 1u) != 0u) & needm & ful0 & aok0;
        const bool el1 = (((cw >> (shift + 1)) & 1u) != 0u) & needm & ful1 & aok1;
        const float fd0 = ((snu & f0) == 0u) ? fdb : 0.f;
        const float fd1 = ((snu & f1) == 0u) ? fdb : 0.f;
        const float lg0 = bl0 + qmv.x * cr0.x + qmv.y * cr0.y + qmv.z * cr0.z + qmv.w * cr0.w + add + fd0;
        const float lg1 = bl1 + qmv.x * cr1.x + qmv.y * cr1.y + qmv.z * cr1.z + qmv.w * cr1.w + add + fd1;
        const unsigned uinv = ~(unsigned)(u0 + uu);
        if (el0) {
            ull kk = ((ull)monof(lg0) << 32) | uinv;
            k0 = k0 > kk ? k0 : kk;
            e0 += __expf(lg0);
        }
        if (el1) {
            ull kk = ((ull)monof(lg1) << 32) | uinv;
            k1 = k1 > kk ? k1 : kk;
            e1 += __expf(lg1);
        }
    }
    const size_t p = (size_t)ublk * (B_N * S_N) + bs;
    ulonglong2 kp; kp.x = k0; kp.y = k1;
    *(ulonglong2*)(keypart + p) = kp;
    *(float2*)(sumpart + p) = make_float2(e0, e1);
}

// ---------- K2: block per batch b. Reduce 64 partials/server, resolve proposals in LDS,
// then apply accepted users. No global flags needed (natural-freeze == reference go).
__global__ __launch_bounds__(1024) void iter_midapply(
    const ull* __restrict__ keypart, const float* __restrict__ sumpart,
    const unsigned* __restrict__ fdm_, const float* __restrict__ nds,
    uint4* __restrict__ alloc3, unsigned* __restrict__ allocU,
    unsigned* __restrict__ rcArr, unsigned* __restrict__ seenArr,
    float* __restrict__ capA, float* __restrict__ logp) {
    __shared__ ull ukeyL[2048];
    __shared__ unsigned sgL[2048];
    __shared__ ull bkL[512];
    __shared__ float bsL[512];
    __shared__ float lpL[512];
    const int b = blockIdx.x, t = threadIdx.x;
    ukeyL[t] = 0ULL; ukeyL[t + 1024] = 0ULL;
    sgL[t] = 0u; sgL[t + 1024] = 0u;
    __syncthreads();
    const int s = t & 511, h = t >> 9;
    const int base = b * S_N + s;
    ull best = 0ULL; float ssum = 0.f;
    #pragma unroll 8
    for (int j = h * 32; j < h * 32 + 32; ++j) {
        ull k = keypart[(size_t)j * (B_N * S_N) + base];
        best = k > best ? k : best;
        ssum += sumpart[(size_t)j * (B_N * S_N) + base];
    }
    if (h == 0) { bkL[s] = best; bsL[s] = ssum; }
    __syncthreads();
    if (h == 1) {
        ull ob = bkL[s];
        best = ob > best ? ob : best;
        ssum += bsL[s];
        if (best != 0ULL) {
            const float mx = unmonof((unsigned)(best >> 32));
            const unsigned pu = ~(unsigned)best;       // winning user (ties -> smallest u)
            lpL[s] = mx - __logf(ssum);                // max - logsumexp
            ull pk = ((ull)monof(mx) << 32) | (~(unsigned)s);
            atomicMax(&ukeyL[pu], pk);
            atomicOr(&sgL[pu], fdm_[base]);
        }
    }
    __syncthreads();
    #pragma unroll
    for (int g = 0; g < 2; ++g) {
        const int u = t + g * 1024;
        const ull key = ukeyL[u];
        if (key != 0ULL) {
            const int gu = b * U_N + u;
            const unsigned s2 = ~(unsigned)key;        // accepted server (ties -> smallest s)
            const int bs2 = b * S_N + (int)s2;
            uint4 al = alloc3[gu];
            const unsigned r = rcArr[gu];
            if (r == 0u) al.x = s2; else if (r == 1u) al.y = s2; else al.z = s2;
            alloc3[gu] = al;
            allocU[gu * 16 + (s2 >> 5)] |= 1u << (s2 & 31u);
            const float4 nd = ((const float4*)nds)[gu];
            float4 cv = ((float4*)capA)[bs2];          // accepted servers distinct per iter
            cv.x = fmaxf(cv.x - nd.x, 0.f); cv.y = fmaxf(cv.y - nd.y, 0.f);
            cv.z = fmaxf(cv.z - nd.z, 0.f); cv.w = fmaxf(cv.w - nd.w, 0.f);
            ((float4*)capA)[bs2] = cv;
            rcArr[gu] = r + 1u;
            logp[gu] += lpL[s2];
            seenArr[gu] |= sgL[u];
        }
    }
}

// ---------- finalize ----------
__global__ void finalize_logp(const float* __restrict__ logp, float* __restrict__ out) {
    int b = blockIdx.x, t = threadIdx.x;
    float s = 0.f;
    for (int u = t; u < U_N; u += 256) s += logp[b * U_N + u];
    #pragma unroll
    for (int m = 1; m < 64; m <<= 1) s += __shfl_xor(s, m, 64);
    __shared__ float r[4];
    if ((t & 63) == 0) r[t >> 6] = s;
    __syncthreads();
    if (t == 0) out[b] = r[0] + r[1] + r[2] + r[3];
}

__global__ void finalize_alloc(const unsigned* __restrict__ allocU, float* __restrict__ out) {
    int idx = blockIdx.x * 256 + threadIdx.x;  // B*U*S/4
    int bu = idx >> 7;
    int s4 = (idx & 127) * 4;
    unsigned w = allocU[bu * 16 + (s4 >> 5)];
    float4 o;
    o.x = ((w >> ((s4 + 0) & 31)) & 1u) ? 1.f : 0.f;
    o.y = ((w >> ((s4 + 1) & 31)) & 1u) ? 1.f : 0.f;
    o.z = ((w >> ((s4 + 2) & 31)) & 1u) ? 1.f : 0.f;
    o.w = ((w >> ((s4 + 3) & 31)) & 1u) ? 1.f : 0.f;
    *(float4*)(out + 16 + (size_t)bu * S_N + s4) = o;
}

__global__ void finalize_cap(const float* __restrict__ capA, float* __restrict__ out) {
    int i = blockIdx.x * 256 + threadIdx.x;
    if (i < B_N * S_N * 4) out[16 + (size_t)B_N * U_N * S_N + i] = capA[i];
}

extern "C" void kernel_launch(void* const* d_in, const int* in_sizes, int n_in,
                              void* d_out, int out_size, void* d_ws, size_t ws_size,
                              hipStream_t stream) {
    const float* user_enc = (const float*)d_in[0];
    const float* server_enc = (const float*)d_in[1];
    const float* users = (const float*)d_in[2];
    const float* servers = (const float*)d_in[3];
    const int* connect = (const int*)d_in[4];
    const int* fd_onehot = (const int*)d_in[5];
    const float* state_proj_w = (const float*)d_in[6];
    const float* state_proj_b = (const float*)d_in[7];
    const float* fd_bias = (const float*)d_in[8];
    const float* ptr_q_w = (const float*)d_in[9];
    const float* ptr_k_w = (const float*)d_in[10];
    const float* user_state_w = (const float*)d_in[11];
    const float* score_bias = (const float*)d_in[12];
    float* out = (float*)d_out;

    char* w = (char*)d_ws;
    _Float16* qkh = (_Float16*)(w + 0);                    // (B,U,S) fp16 33554432 B
    float* q = (float*)(w + 33554432);                     // (B,U,D) fp32 16777216 B
    unsigned short* qb = (unsigned short*)(w + 50331648);  // (B,U,D) bf16 8388608 B
    unsigned short* kb = (unsigned short*)(w + 58720256);  // (B,S,D) bf16 2097152 B
    ull* keypart = (ull*)(w + 60817408);                   // (64,B*S) 4194304 B
    float* sumpart = (float*)(w + 65011712);               // (64,B*S) 2097152 B
    float* qm = (float*)(w + 67108864);                    // (B,U,4) 524288 B
    ull* connU = (ull*)(w + 67633152);                     // (B,U,8) 2097152 B
    unsigned* allocU = (unsigned*)(w + 69730304);          // (B,U,16) 2097152 B
    uint4* alloc3 = (uint4*)(w + 71827456);                // (B,U) 524288 B
    float* nds = (float*)(w + 72351744);                   // (B,U,4) 524288 B
    unsigned* fdm = (unsigned*)(w + 72876032);             // (B,S) 32768 B
    float* capA = (float*)(w + 72908800);                  // (B,S,4) 131072 B
    float* invA = (float*)(w + 73039872);                  // (B,S,4) 131072 B
    unsigned* rcArr = (unsigned*)(w + 73170944);           // (B,U) 131072 B
    unsigned* seenArr = (unsigned*)(w + 73302016);         // (B,U) 131072 B
    float* logp = (float*)(w + 73433088);                  // (B,U) 131072 B
    float* M2 = (float*)(w + 73564160);                    // (D,4) 2048 B

    init_state<<<2048, 256, 0, stream>>>(servers, users, fd_onehot, allocU, alloc3, rcArr,
                                         seenArr, logp, capA, invA, fdm, nds);
    pack_connect<<<8192, 256, 0, stream>>>(connect, connU);
    // kb (bf16) = inv_sqrt_d * (server_enc + spb) @ ptr_k_w^T
    gemm_nt<true, 1><<<dim3(8, 2, 16), 256, 0, stream>>>(server_enc, ptr_k_w, state_proj_b,
                                                         nullptr, kb, S_N, D_N, D_N, INV_SQRT_D);
    // q (fp32 + bf16) = user_enc @ ptr_q_w^T
    gemm_nt<false, 2><<<dim3(32, 2, 16), 256, 0, stream>>>(user_enc, ptr_q_w, nullptr,
                                                           q, qb, U_N, D_N, D_N, 1.0f);
    m2_kernel<<<1, 512, 0, stream>>>(ptr_k_w, state_proj_w, M2);
    qm_kernel<<<dim3(32, 16), 256, 0, stream>>>(q, M2, qm);
    // qkh[b][u][s] = fp16( qb[b][u] . kb[b][s] )
    qk_mfma<<<dim3(16, 8, 16), 256, 0, stream>>>(qb, kb, qkh);
    for (int it = 0; it < 16; ++it) {
        iter_score<<<1024, 256, 0, stream>>>(qkh, qm, nds, (const unsigned*)connU, alloc3, rcArr,
                                             seenArr, fdm, capA, invA, user_state_w, score_bias,
                                             fd_bias, keypart, sumpart);
        iter_midapply<<<16, 1024, 0, stream>>>(keypart, sumpart, fdm, nds, alloc3, allocU,
                                               rcArr, seenArr, capA, logp);
    }
    finalize_logp<<<16, 256, 0, stream>>>(logp, out);
    finalize_alloc<<<16384, 256, 0, stream>>>(allocU, out);
    finalize_cap<<<128, 256, 0, stream>>>(capA, out);
}

// Round 4
// 498.231 us; speedup vs baseline: 1.3700x; 1.3700x over previous
//
#include <hip/hip_runtime.h>
#include <hip/hip_bf16.h>

#define B_N 16
#define U_N 2048
#define S_N 512
#define D_N 128
#define INV_SQRT_D 0.08838834764831845f

typedef unsigned long long ull;
typedef __attribute__((ext_vector_type(8))) short bf16x8;
typedef __attribute__((ext_vector_type(4))) float f32x4;
typedef __attribute__((ext_vector_type(4))) _Float16 f16x4;

// ---------- helpers ----------
__device__ __forceinline__ unsigned monof(float v) {
    unsigned b = __float_as_uint(v);
    return (b & 0x80000000u) ? ~b : (b | 0x80000000u);
}
__device__ __forceinline__ float unmonof(unsigned m) {
    unsigned b = (m & 0x80000000u) ? (m & 0x7fffffffu) : ~m;
    return __uint_as_float(b);
}
__device__ __forceinline__ unsigned short f2bf(float x) {  // RNE fp32->bf16
    unsigned u = __float_as_uint(x);
    return (unsigned short)((u + 0x7fffu + ((u >> 16) & 1u)) >> 16);
}

// ---------- init: zero state, pack needs/caps/fd masks ----------
__global__ void init_state(const float* __restrict__ servers, const float* __restrict__ users,
                           const int* __restrict__ fd_onehot,
                           unsigned* allocU, uint4* alloc3, unsigned* rcArr, unsigned* seenArr,
                           float* logp, float* capA, float* invA, unsigned* fdm, float* nds,
                           unsigned* any_valid) {
    int i = blockIdx.x * 256 + threadIdx.x;  // 2048 blocks -> 524288 threads
    if (i < B_N * U_N * 16) allocU[i] = 0u;
    if (i < B_N * U_N) {
        rcArr[i] = 0u; seenArr[i] = 0u; logp[i] = 0.f;
        alloc3[i] = make_uint4(0xFFFFFFFFu, 0xFFFFFFFFu, 0xFFFFFFFFu, 0xFFFFFFFFu);
        const float* up = users + (size_t)i * 6;
        nds[i * 4 + 0] = up[2]; nds[i * 4 + 1] = up[3];
        nds[i * 4 + 2] = up[4]; nds[i * 4 + 3] = up[5];
    }
    if (i < B_N * S_N) {
        const float* sp = servers + (size_t)i * 7;
        float4 c = make_float4(sp[3], sp[4], sp[5], sp[6]);
        ((float4*)capA)[i] = c;
        ((float4*)invA)[i] = make_float4(1.f / fmaxf(c.x, 1e-6f), 1.f / fmaxf(c.y, 1e-6f),
                                         1.f / fmaxf(c.z, 1e-6f), 1.f / fmaxf(c.w, 1e-6f));
        unsigned w = 0u;
        const int* fp = fd_onehot + (size_t)i * 32;
        #pragma unroll
        for (int f = 0; f < 32; ++f) w |= (fp[f] != 0 ? 1u : 0u) << f;
        fdm[i] = w;
    }
    if (i < 16) any_valid[i] = 0u;
}

// ---------- pack connect (B,U,S) int32 -> (B,U,S-bits): ballot per wave ----------
__global__ void pack_connect(const int* __restrict__ connect, ull* __restrict__ connU) {
    int i = blockIdx.x * 4 + (threadIdx.x >> 6);  // row index in [0, B*U)
    int lane = threadIdx.x & 63;
    const int* row = connect + (size_t)i * S_N;
    #pragma unroll
    for (int c = 0; c < 8; ++c) {
        ull m = __ballot(row[c * 64 + lane] != 0);
        if (lane == 0) connU[(size_t)i * 8 + c] = m;
    }
}

// ---------- generic fp32 GEMM: C[z][m][n] = scale * sum_k (A[z][m][k](+abias[k])) * B[n][k]
// OUTMODE: 0 = fp32 only, 1 = bf16 only, 2 = both
template <bool ABIAS, int OUTMODE>
__global__ __launch_bounds__(256) void gemm_nt(const float* __restrict__ A, const float* __restrict__ Bm,
                                               const float* __restrict__ abias, float* __restrict__ C,
                                               unsigned short* __restrict__ C16,
                                               int M, int N, int K, float scale) {
    __shared__ float As[16][68];
    __shared__ float Bs[16][68];
    int z = blockIdx.z;
    const float* Ab = A + (size_t)z * M * K;
    const float* Bb = Bm;
    int m0 = blockIdx.x * 64, n0 = blockIdx.y * 64;
    int tid = threadIdx.x;
    int tx = tid & 15, ty = tid >> 4;
    int lrow = tid >> 2, lk = (tid & 3) * 4;
    float acc[4][4] = {};
    for (int k0 = 0; k0 < K; k0 += 16) {
        float4 av = *(const float4*)(Ab + (size_t)(m0 + lrow) * K + k0 + lk);
        float4 bv = *(const float4*)(Bb + (size_t)(n0 + lrow) * K + k0 + lk);
        if (ABIAS) {
            av.x += abias[k0 + lk]; av.y += abias[k0 + lk + 1];
            av.z += abias[k0 + lk + 2]; av.w += abias[k0 + lk + 3];
        }
        __syncthreads();
        As[lk + 0][lrow] = av.x; As[lk + 1][lrow] = av.y; As[lk + 2][lrow] = av.z; As[lk + 3][lrow] = av.w;
        Bs[lk + 0][lrow] = bv.x; Bs[lk + 1][lrow] = bv.y; Bs[lk + 2][lrow] = bv.z; Bs[lk + 3][lrow] = bv.w;
        __syncthreads();
        #pragma unroll
        for (int kk = 0; kk < 16; ++kk) {
            float4 a = *(const float4*)&As[kk][ty * 4];
            float4 bq = *(const float4*)&Bs[kk][tx * 4];
            float ar[4] = {a.x, a.y, a.z, a.w}, br[4] = {bq.x, bq.y, bq.z, bq.w};
            #pragma unroll
            for (int ii = 0; ii < 4; ++ii)
                #pragma unroll
                for (int jj = 0; jj < 4; ++jj) acc[ii][jj] += ar[ii] * br[jj];
        }
    }
    #pragma unroll
    for (int ii = 0; ii < 4; ++ii) {
        float4 o = make_float4(acc[ii][0] * scale, acc[ii][1] * scale,
                               acc[ii][2] * scale, acc[ii][3] * scale);
        size_t idx = (size_t)z * M * N + (size_t)(m0 + ty * 4 + ii) * N + n0 + tx * 4;
        if (OUTMODE != 1) *(float4*)(C + idx) = o;
        if (OUTMODE != 0) {
            ushort4 ob;
            ob.x = f2bf(o.x); ob.y = f2bf(o.y); ob.z = f2bf(o.z); ob.w = f2bf(o.w);
            *(ushort4*)(C16 + idx) = ob;
        }
    }
}

// ---------- M2[d][c] = inv_sqrt_d * sum_e ptr_k_w[d,e]*state_proj_w[e,c] ----------
__global__ void m2_kernel(const float* __restrict__ kw, const float* __restrict__ spw, float* __restrict__ M2) {
    int t = threadIdx.x;
    if (t < 512) {
        int d = t >> 2, c = t & 3;
        float acc = 0.f;
        for (int e = 0; e < 128; ++e) acc += kw[d * 128 + e] * spw[e * 4 + c];
        M2[t] = acc * INV_SQRT_D;
    }
}

// ---------- qm[b,u,c] = sum_d q[b,u,d]*M2[d,c] ----------
__global__ void qm_kernel(const float* __restrict__ q, const float* __restrict__ M2, float* __restrict__ qm) {
    __shared__ float qs[64][129];
    __shared__ float m2s[512];
    int b = blockIdx.y, u0 = blockIdx.x * 64;
    int t = threadIdx.x;
    for (int i = t; i < 512; i += 256) m2s[i] = M2[i];
    #pragma unroll
    for (int it = 0; it < 8; ++it) {
        int f4 = t + 256 * it;
        int row = f4 >> 5;
        int col = (f4 & 31) * 4;
        float4 v = *(const float4*)(q + ((size_t)(b * U_N + u0 + row)) * D_N + col);
        qs[row][col] = v.x; qs[row][col + 1] = v.y; qs[row][col + 2] = v.z; qs[row][col + 3] = v.w;
    }
    __syncthreads();
    int ul = t >> 2, c = t & 3;
    float acc = 0.f;
    for (int d = 0; d < 128; ++d) acc += qs[ul][d] * m2s[d * 4 + c];
    qm[((size_t)(b * U_N + u0 + ul)) * 4 + c] = acc;
}

// ---------- qk MFMA: qkh[b][u][s] = fp16( sum_k qb[b][u][k]*kb[b][s][k] ), bf16 inputs. ----------
__global__ __launch_bounds__(256) void qk_mfma(const unsigned short* __restrict__ qb,
                                               const unsigned short* __restrict__ kb,
                                               _Float16* __restrict__ qkh) {
    const int b = blockIdx.z, u0 = blockIdx.x * 128, s0 = blockIdx.y * 64;
    const int t = threadIdx.x, w = t >> 6, l = t & 63;
    const int lr = l & 15, lq = l >> 4;
    const unsigned short* Ab = qb + ((size_t)(b * U_N + u0 + w * 32 + lr)) * D_N + lq * 8;
    const unsigned short* Bb = kb + ((size_t)(b * S_N + s0 + lr)) * D_N + lq * 8;
    f32x4 acc[2][4] = {};
    #pragma unroll
    for (int kt = 0; kt < 4; ++kt) {
        bf16x8 a0 = *(const bf16x8*)(Ab + kt * 32);
        bf16x8 a1 = *(const bf16x8*)(Ab + 16 * D_N + kt * 32);
        #pragma unroll
        for (int c = 0; c < 4; ++c) {
            bf16x8 bf = *(const bf16x8*)(Bb + c * 16 * D_N + kt * 32);
            acc[0][c] = __builtin_amdgcn_mfma_f32_16x16x32_bf16(a0, bf, acc[0][c], 0, 0, 0);
            acc[1][c] = __builtin_amdgcn_mfma_f32_16x16x32_bf16(a1, bf, acc[1][c], 0, 0, 0);
        }
    }
    __shared__ _Float16 Cs[128][72];
    #pragma unroll
    for (int mt = 0; mt < 2; ++mt)
        #pragma unroll
        for (int c = 0; c < 4; ++c)
            #pragma unroll
            for (int r = 0; r < 4; ++r)
                Cs[w * 32 + mt * 16 + lq * 4 + r][c * 16 + lr] = (_Float16)acc[mt][c][r];
    __syncthreads();
    #pragma unroll
    for (int k = 0; k < 4; ++k) {
        int row = (t >> 3) + k * 32;
        int sg = (t & 7) * 8;
        uint4 v = *(const uint4*)&Cs[row][sg];
        *(uint4*)(qkh + ((size_t)(b * U_N + u0 + row)) * S_N + s0 + sg) = v;
    }
}

// ---------- K1: scoring. block = (b, 32 users); thread owns 4 servers; 2 user-halves.
// Per-server running (max-key, exp-sum) in registers; halves merged via LDS.
__global__ __launch_bounds__(256) void iter_score(
    const _Float16* __restrict__ qkh, const float* __restrict__ qm4,
    const float* __restrict__ nds, const unsigned* __restrict__ connU32,
    const uint4* __restrict__ alloc3, const unsigned* __restrict__ rcArr,
    const unsigned* __restrict__ seenArr, const unsigned* __restrict__ fdm_,
    const float* __restrict__ capA, const float* __restrict__ invA,
    const float* __restrict__ usw, const float* __restrict__ sbp, const float* __restrict__ fdbp,
    ull* __restrict__ keypart, float* __restrict__ sumpart,
    const unsigned* __restrict__ any_valid, int iter) {
    if (iter > 0 && any_valid[iter - 1] == 0u) return;   // frozen chain
    const int tid = threadIdx.x;
    const int b = blockIdx.x & 15;        // b%8 -> XCD pinning for qk L2 locality
    const int ublk = blockIdx.x >> 4;     // 0..63, 32 users each
    const int u0 = ublk << 5;
    const int h = tid >> 7;               // user half (16 users each)
    const int sl = tid & 127;             // server quad: servers 4sl..4sl+3
    const int s0 = sl * 4;
    const float w0 = usw[0], w1 = usw[1], w2 = usw[2], sb = sbp[0], fdb = fdbp[0];
    const float ub0 = sb + w1;                                      // rc=0
    const float ub1 = sb + w0 * (1.f / 3.f) + w1 * (2.f / 3.f);     // rc=1
    const float ub2 = sb + w0 * (2.f / 3.f) + w1 * (1.f / 3.f) + w2; // rc=2
    const int bsb = b * S_N + s0;
    float4 cap[4], cr[4]; unsigned fq[4];
    #pragma unroll
    for (int j = 0; j < 4; ++j) {
        cap[j] = ((const float4*)capA)[bsb + j];
        float4 iv = ((const float4*)invA)[bsb + j];
        cr[j] = make_float4(cap[j].x * iv.x, cap[j].y * iv.y, cap[j].z * iv.z, cap[j].w * iv.w);
        fq[j] = fdm_[bsb + j];
    }
    ull k[4] = {0ULL, 0ULL, 0ULL, 0ULL};
    float e[4] = {0.f, 0.f, 0.f, 0.f};
    const int gub = b * U_N + u0 + h * 16;
    const _Float16* qkbase = qkh + ((size_t)gub) * S_N + s0;
    const int cwbase = gub * 16 + (sl >> 3);
    const int nsh = (sl & 7) * 4;
    #pragma unroll 2
    for (int uu = 0; uu < 16; ++uu) {
        const int gu = gub + uu;
        const unsigned rcu = rcArr[gu];               // wave-uniform scalar load
        if (rcu < 3u) {                                // uniform skip: saturated users free
            const f16x4 qv = *(const f16x4*)(qkbase + (size_t)uu * S_N);
            const float4 qmv = ((const float4*)qm4)[gu];
            const float4 ndv = ((const float4*)nds)[gu];
            const unsigned snu = seenArr[gu];
            const uint4 al = alloc3[gu];
            const unsigned nib = connU32[cwbase + uu * 16] >> nsh;
            const float add = (rcu == 0u) ? ub0 : ((rcu == 1u) ? ub1 : ub2);
            const unsigned uinv = ~(unsigned)(u0 + h * 16 + uu);
            #pragma unroll
            for (int j = 0; j < 4; ++j) {
                const unsigned us = (unsigned)(s0 + j);
                const bool ful = (cap[j].x >= ndv.x) & (cap[j].y >= ndv.y) &
                                 (cap[j].z >= ndv.z) & (cap[j].w >= ndv.w);
                const bool aok = (al.x != us) & (al.y != us) & (al.z != us);
                const bool el = (((nib >> j) & 1u) != 0u) & ful & aok;
                const float lg = (float)qv[j] + qmv.x * cr[j].x + qmv.y * cr[j].y +
                                 qmv.z * cr[j].z + qmv.w * cr[j].w + add +
                                 (((snu & fq[j]) == 0u) ? fdb : 0.f);
                if (el) {
                    const ull kk = ((ull)monof(lg) << 32) | uinv;
                    k[j] = k[j] > kk ? k[j] : kk;
                    e[j] += __expf(lg);
                }
            }
        }
    }
    // merge the two user-halves via LDS (6 KB)
    __shared__ ull mk[128][4];
    __shared__ float me[128][4];
    if (h == 1) {
        #pragma unroll
        for (int j = 0; j < 4; ++j) { mk[sl][j] = k[j]; me[sl][j] = e[j]; }
    }
    __syncthreads();
    if (h == 0) {
        #pragma unroll
        for (int j = 0; j < 4; ++j) {
            const ull o = mk[sl][j];
            k[j] = o > k[j] ? o : k[j];
            e[j] += me[sl][j];
        }
        const size_t p = (size_t)ublk * (B_N * S_N) + bsb;
        ulonglong2 ka; ka.x = k[0]; ka.y = k[1];
        ulonglong2 kc; kc.x = k[2]; kc.y = k[3];
        *(ulonglong2*)(keypart + p) = ka;
        *(ulonglong2*)(keypart + p + 2) = kc;
        *(float4*)(sumpart + p) = make_float4(e[0], e[1], e[2], e[3]);
    }
}

// ---------- K2: block per batch. Reduce 64 partials/server, resolve proposals in LDS, apply. ----------
__global__ __launch_bounds__(1024) void iter_midapply(
    const ull* __restrict__ keypart, const float* __restrict__ sumpart,
    const unsigned* __restrict__ fdm_, const float* __restrict__ nds,
    uint4* __restrict__ alloc3, unsigned* __restrict__ allocU,
    unsigned* __restrict__ rcArr, unsigned* __restrict__ seenArr,
    float* __restrict__ capA, float* __restrict__ logp,
    unsigned* __restrict__ any_valid, int iter) {
    if (iter > 0 && any_valid[iter - 1] == 0u) return;   // frozen chain
    __shared__ ull ukeyL[2048];
    __shared__ unsigned sgL[2048];
    __shared__ ull bkL[512];
    __shared__ float bsL[512];
    __shared__ float lpL[512];
    const int b = blockIdx.x, t = threadIdx.x;
    ukeyL[t] = 0ULL; ukeyL[t + 1024] = 0ULL;
    sgL[t] = 0u; sgL[t + 1024] = 0u;
    __syncthreads();
    const int s = t & 511, h = t >> 9;
    const int base = b * S_N + s;
    ull best = 0ULL; float ssum = 0.f;
    #pragma unroll 16
    for (int j = h * 32; j < h * 32 + 32; ++j) {
        const ull kk = keypart[(size_t)j * (B_N * S_N) + base];
        best = kk > best ? kk : best;
        ssum += sumpart[(size_t)j * (B_N * S_N) + base];
    }
    if (h == 0) { bkL[s] = best; bsL[s] = ssum; }
    __syncthreads();
    unsigned prop = 0u;
    if (h == 1) {
        const ull ob = bkL[s];
        best = ob > best ? ob : best;
        ssum += bsL[s];
        if (best != 0ULL) {
            const float mx = unmonof((unsigned)(best >> 32));
            const unsigned pu = ~(unsigned)best;       // winning user (ties -> smallest u)
            lpL[s] = mx - __logf(ssum);                // max - logsumexp
            const ull pk = ((ull)monof(mx) << 32) | (~(unsigned)s);
            atomicMax(&ukeyL[pu], pk);
            atomicOr(&sgL[pu], fdm_[base]);
            prop = 1u;
        }
    }
    const ull bal = __ballot(prop != 0u);
    if (bal != 0ULL && (t & 63) == 0) atomicOr(&any_valid[iter], 1u);
    __syncthreads();
    #pragma unroll
    for (int g = 0; g < 2; ++g) {
        const int u = t + g * 1024;
        const ull key = ukeyL[u];
        if (key != 0ULL) {                             // user received >=1 proposal -> accepts
            const int gu = b * U_N + u;
            const unsigned s2 = ~(unsigned)key;        // accepted server (ties -> smallest s)
            const int bs2 = b * S_N + (int)s2;
            uint4 al = alloc3[gu];
            const unsigned r = rcArr[gu];
            if (r == 0u) al.x = s2; else if (r == 1u) al.y = s2; else al.z = s2;
            alloc3[gu] = al;
            allocU[gu * 16 + (s2 >> 5)] |= 1u << (s2 & 31u);
            const float4 nd = ((const float4*)nds)[gu];
            float4 cv = ((float4*)capA)[bs2];          // accepted servers distinct per iter
            cv.x = fmaxf(cv.x - nd.x, 0.f); cv.y = fmaxf(cv.y - nd.y, 0.f);
            cv.z = fmaxf(cv.z - nd.z, 0.f); cv.w = fmaxf(cv.w - nd.w, 0.f);
            ((float4*)capA)[bs2] = cv;
            rcArr[gu] = r + 1u;
            logp[gu] += lpL[s2];
            seenArr[gu] |= sgL[u];
        }
    }
}

// ---------- finalize ----------
__global__ void finalize_logp(const float* __restrict__ logp, float* __restrict__ out) {
    int b = blockIdx.x, t = threadIdx.x;
    float s = 0.f;
    for (int u = t; u < U_N; u += 256) s += logp[b * U_N + u];
    #pragma unroll
    for (int m = 1; m < 64; m <<= 1) s += __shfl_xor(s, m, 64);
    __shared__ float r[4];
    if ((t & 63) == 0) r[t >> 6] = s;
    __syncthreads();
    if (t == 0) out[b] = r[0] + r[1] + r[2] + r[3];
}

__global__ void finalize_alloc(const unsigned* __restrict__ allocU, float* __restrict__ out) {
    int idx = blockIdx.x * 256 + threadIdx.x;  // B*U*S/4
    int bu = idx >> 7;
    int s4 = (idx & 127) * 4;
    unsigned w = allocU[bu * 16 + (s4 >> 5)];
    float4 o;
    o.x = ((w >> ((s4 + 0) & 31)) & 1u) ? 1.f : 0.f;
    o.y = ((w >> ((s4 + 1) & 31)) & 1u) ? 1.f : 0.f;
    o.z = ((w >> ((s4 + 2) & 31)) & 1u) ? 1.f : 0.f;
    o.w = ((w >> ((s4 + 3) & 31)) & 1u) ? 1.f : 0.f;
    *(float4*)(out + 16 + (size_t)bu * S_N + s4) = o;
}

__global__ void finalize_cap(const float* __restrict__ capA, float* __restrict__ out) {
    int i = blockIdx.x * 256 + threadIdx.x;
    if (i < B_N * S_N * 4) out[16 + (size_t)B_N * U_N * S_N + i] = capA[i];
}

extern "C" void kernel_launch(void* const* d_in, const int* in_sizes, int n_in,
                              void* d_out, int out_size, void* d_ws, size_t ws_size,
                              hipStream_t stream) {
    const float* user_enc = (const float*)d_in[0];
    const float* server_enc = (const float*)d_in[1];
    const float* users = (const float*)d_in[2];
    const float* servers = (const float*)d_in[3];
    const int* connect = (const int*)d_in[4];
    const int* fd_onehot = (const int*)d_in[5];
    const float* state_proj_w = (const float*)d_in[6];
    const float* state_proj_b = (const float*)d_in[7];
    const float* fd_bias = (const float*)d_in[8];
    const float* ptr_q_w = (const float*)d_in[9];
    const float* ptr_k_w = (const float*)d_in[10];
    const float* user_state_w = (const float*)d_in[11];
    const float* score_bias = (const float*)d_in[12];
    float* out = (float*)d_out;

    char* w = (char*)d_ws;
    _Float16* qkh = (_Float16*)(w + 0);                    // (B,U,S) fp16 33554432 B
    float* q = (float*)(w + 33554432);                     // (B,U,D) fp32 16777216 B
    unsigned short* qb = (unsigned short*)(w + 50331648);  // (B,U,D) bf16 8388608 B
    unsigned short* kb = (unsigned short*)(w + 58720256);  // (B,S,D) bf16 2097152 B
    ull* keypart = (ull*)(w + 60817408);                   // (64,B*S) 4194304 B
    float* sumpart = (float*)(w + 65011712);               // (64,B*S) 2097152 B
    float* qm = (float*)(w + 67108864);                    // (B,U,4) 524288 B
    ull* connU = (ull*)(w + 67633152);                     // (B,U,8) 2097152 B
    unsigned* allocU = (unsigned*)(w + 69730304);          // (B,U,16) 2097152 B
    uint4* alloc3 = (uint4*)(w + 71827456);                // (B,U) 524288 B
    float* nds = (float*)(w + 72351744);                   // (B,U,4) 524288 B
    unsigned* fdm = (unsigned*)(w + 72876032);             // (B,S) 32768 B
    float* capA = (float*)(w + 72908800);                  // (B,S,4) 131072 B
    float* invA = (float*)(w + 73039872);                  // (B,S,4) 131072 B
    unsigned* rcArr = (unsigned*)(w + 73170944);           // (B,U) 131072 B
    unsigned* seenArr = (unsigned*)(w + 73302016);         // (B,U) 131072 B
    float* logp = (float*)(w + 73433088);                  // (B,U) 131072 B
    float* M2 = (float*)(w + 73564160);                    // (D,4) 2048 B
    unsigned* any_valid = (unsigned*)(w + 73566208);       // 16

    init_state<<<2048, 256, 0, stream>>>(servers, users, fd_onehot, allocU, alloc3, rcArr,
                                         seenArr, logp, capA, invA, fdm, nds, any_valid);
    pack_connect<<<8192, 256, 0, stream>>>(connect, connU);
    // kb (bf16) = inv_sqrt_d * (server_enc + spb) @ ptr_k_w^T
    gemm_nt<true, 1><<<dim3(8, 2, 16), 256, 0, stream>>>(server_enc, ptr_k_w, state_proj_b,
                                                         nullptr, kb, S_N, D_N, D_N, INV_SQRT_D);
    // q (fp32 + bf16) = user_enc @ ptr_q_w^T
    gemm_nt<false, 2><<<dim3(32, 2, 16), 256, 0, stream>>>(user_enc, ptr_q_w, nullptr,
                                                           q, qb, U_N, D_N, D_N, 1.0f);
    m2_kernel<<<1, 512, 0, stream>>>(ptr_k_w, state_proj_w, M2);
    qm_kernel<<<dim3(32, 16), 256, 0, stream>>>(q, M2, qm);
    // qkh[b][u][s] = fp16( qb[b][u] . kb[b][s] )
    qk_mfma<<<dim3(16, 8, 16), 256, 0, stream>>>(qb, kb, qkh);
    for (int it = 0; it < 16; ++it) {
        iter_score<<<1024, 256, 0, stream>>>(qkh, qm, nds, (const unsigned*)connU, alloc3, rcArr,
                                             seenArr, fdm, capA, invA, user_state_w, score_bias,
                                             fd_bias, keypart, sumpart, any_valid, it);
        iter_midapply<<<16, 1024, 0, stream>>>(keypart, sumpart, fdm, nds, alloc3, allocU,
                                               rcArr, seenArr, capA, logp, any_valid, it);
    }
    finalize_logp<<<16, 256, 0, stream>>>(logp, out);
    finalize_alloc<<<16384, 256, 0, stream>>>(allocU, out);
    finalize_cap<<<128, 256, 0, stream>>>(capA, out);
}